// Round 16
// baseline (134.752 us; speedup 1.0000x reference)
//
#include <hip/hip_runtime.h>
#include <math.h>

// FlowMatchingLoss: B=8, M=K=2048. Log-domain pre-scaled by log2e (hw exp2/log2).
//   K_log' = sc_b * c,  sc_b = -20*log2e/(cmax_b+1e-8)
// Round-16: REGISTER-RESIDENT POTENTIALS. Each lane owns 16 fixed k-pairs
// (p = lane + 64i); its 16 potential pairs are loaded upfront per pass as
// 8B relaxed-agent atomic loads (L3-coherent) into registers -- the per-pass
// LDS staging loop, its __syncthreads, and the swf array disappear. Inner
// loop reads the resident n2 pair and adds the register potential (1 pk-add
// shared by 4 rows). Final pass uses register lv directly for sum(pi*lv).
// Kept from R15: k-pair SoA LDS with loop-invariant row broadcasts, per-batch
// fence-free barriers, relaxed-agent L3 routing, tail-counter combine.

#define LOG2E 1.4426950408889634f
#define TAU   0.95238095238095238f     // 1/(1+0.05)
#define NEG20LOG2E (-28.853900817779268f)

typedef float v2f __attribute__((ext_vector_type(2)));

// workspace layout, 4-byte units
enum : int {
  OFF_LU    = 0,        // 16384: log_u * log2e   (L3-resident via atomics)
  OFF_LV    = 16384,    // 16384: log_v * log2e
  OFF_CPART = 32768,    // 512 per-block cmax partials (64/batch)
  OFF_SUMAP = 33280,    // 512 per-block sum(a) partials (64/batch)
  OFF_SWP   = 33792,    // 512 per-block sum(w)
  OFF_SEWP  = 34304,    // 512 per-block sum(w*err)
  OFF_FPART = 34816,    // 3*512 final partials (bce, sum_pi, sum_pi*klog)
  OFF_BBAR  = 36352,    // 8 batches x 512: [0..3]*32 arr | 4*32 root | (8+g)*32 rel
  OFF_TAIL  = 40448,    // last-block-done counter (padded slot)
  OFF_END   = 40480
};

__device__ __forceinline__ float fexp2(float x){ return __builtin_amdgcn_exp2f(x); }
__device__ __forceinline__ float flog2(float x){ return __builtin_amdgcn_logf(x); }
__device__ __forceinline__ v2f vfma(v2f a, v2f b, v2f c){
  return __builtin_elementwise_fma(a,b,c);
}

// L3-coherent access (relaxed agent atomics: cache-bypass, no maintenance)
__device__ __forceinline__ float ld3(const float* p){
  return __hip_atomic_load(p, __ATOMIC_RELAXED, __HIP_MEMORY_SCOPE_AGENT);
}
__device__ __forceinline__ v2f ld3x2(const float* p){   // 8B-aligned pair
  const unsigned long long u =
      __hip_atomic_load(reinterpret_cast<const unsigned long long*>(p),
                        __ATOMIC_RELAXED, __HIP_MEMORY_SCOPE_AGENT);
  return __builtin_bit_cast(v2f, u);
}
__device__ __forceinline__ void st3(float* p, float v){
  __hip_atomic_store(p, v, __ATOMIC_RELAXED, __HIP_MEMORY_SCOPE_AGENT);
}

__device__ __forceinline__ float wave_sum(float v){
  #pragma unroll
  for(int m=32;m;m>>=1) v += __shfl_xor(v,m,64);
  return v;
}
__device__ __forceinline__ float wave_max(float v){
  #pragma unroll
  for(int m=32;m;m>>=1) v = fmaxf(v,__shfl_xor(v,m,64));
  return v;
}

// per-batch fence-free barrier: 64 blocks, 4 groups of 16 -> root ->
// 4 release flags; leaders spin on own group's flag (16 pollers/line).
__device__ __forceinline__ void bbar(unsigned* bbase, int phase, int blk){
  __syncthreads();
  if(threadIdx.x == 0){
    asm volatile("s_waitcnt vmcnt(0)" ::: "memory");   // stores reached L3
    const int g = (blk>>4)&3;
    unsigned* garr = bbase + g*32;
    unsigned* root = bbase + 4*32;
    unsigned* grel = bbase + (8+g)*32;
    const unsigned va = __hip_atomic_fetch_add(garr, 1u, __ATOMIC_RELAXED,
                                               __HIP_MEMORY_SCOPE_AGENT);
    if(va == (unsigned)(16*phase - 1)){
      const unsigned vr = __hip_atomic_fetch_add(root, 1u, __ATOMIC_RELAXED,
                                                 __HIP_MEMORY_SCOPE_AGENT);
      if(vr == (unsigned)(4*phase - 1)){
        #pragma unroll
        for(int g2=0; g2<4; ++g2)
          __hip_atomic_store(bbase + (8+g2)*32, (unsigned)phase,
                             __ATOMIC_RELAXED, __HIP_MEMORY_SCOPE_AGENT);
      }
    }
    while(__hip_atomic_load(grel, __ATOMIC_RELAXED, __HIP_MEMORY_SCOPE_AGENT)
          < (unsigned)phase)
      __builtin_amdgcn_s_sleep(1);
    asm volatile("" ::: "memory");
  }
  __syncthreads();
}

__global__ __launch_bounds__(256) void k_init(float* ws){
  unsigned* bar = reinterpret_cast<unsigned*>(ws);
  for(int i=threadIdx.x; i<OFF_END-OFF_BBAR; i+=256) bar[OFF_BBAR+i] = 0u;
}

// one lse half-iteration, k-pair SoA + register potentials. Iterated side in
// LDS scaled (xyz = n2sc*xyz pairs, n2 = sc*|.|^2 pairs). Per-lane potential
// pairs loaded upfront (8B L3-atomic) into pot[16]; inner loop fully unrolled
// (static pot index): per iter 4 b64 LDS + 1 pk-add + per row {3 pk-fma,
// 2 exp2, 2 add}. Row const sc|row|^2 (pass-correct) in the log2 epilogue.
#define LSE_PASS(ROWV, FIRSTV, PH) {                                          \
    const v2f* SX = ROWV ? sxB : sxA;                                         \
    const v2f* SY = ROWV ? syB : syA;                                         \
    const v2f* SZ = ROWV ? szB : szA;                                         \
    const v2f* SN = ROWV ? n2B : n2A;                                         \
    const float4* AF = ROWV ? AR : AC;                                        \
    float* lo = ws + (ROWV?OFF_LV:OFF_LU) + 2048*b;                           \
    float* op = ws + (ROWV?OFF_LU:OFF_LV);                                    \
    v2f pot[16];                                                              \
    if(!FIRSTV){                                                              \
      _Pragma("unroll")                                                       \
      for(int i=0;i<16;i++) pot[i] = ld3x2(lo + 2*(lane + (i<<6)));           \
    }                                                                         \
    const v2f ax0={AF[0].x,AF[0].x}, ay0={AF[0].y,AF[0].y}, az0={AF[0].z,AF[0].z};\
    const v2f ax1={AF[1].x,AF[1].x}, ay1={AF[1].y,AF[1].y}, az1={AF[1].z,AF[1].z};\
    const v2f ax2={AF[2].x,AF[2].x}, ay2={AF[2].y,AF[2].y}, az2={AF[2].z,AF[2].z};\
    const v2f ax3={AF[3].x,AF[3].x}, ay3={AF[3].y,AF[3].y}, az3={AF[3].z,AF[3].z};\
    float sl0=0,sh0=0,sl1=0,sh1=0,sl2=0,sh2=0,sl3=0,sh3=0;                    \
    _Pragma("unroll")                                                         \
    for(int i=0;i<16;i++){                                                    \
      const int p = lane + (i<<6);                                            \
      const v2f xp=SX[p], yp=SY[p], zp=SZ[p];                                 \
      const v2f wp = FIRSTV ? SN[p] : (SN[p] + pot[i]);                       \
      v2f c;                                                                  \
      c = vfma(ax0,xp,vfma(ay0,yp,vfma(az0,zp,wp)));                          \
      sl0 += fexp2(c[0]); sh0 += fexp2(c[1]);                                 \
      c = vfma(ax1,xp,vfma(ay1,yp,vfma(az1,zp,wp)));                          \
      sl1 += fexp2(c[0]); sh1 += fexp2(c[1]);                                 \
      c = vfma(ax2,xp,vfma(ay2,yp,vfma(az2,zp,wp)));                          \
      sl2 += fexp2(c[0]); sh2 += fexp2(c[1]);                                 \
      c = vfma(ax3,xp,vfma(ay3,yp,vfma(az3,zp,wp)));                          \
      sl3 += fexp2(c[0]); sh3 += fexp2(c[1]);                                 \
    }                                                                         \
    const float s0=wave_sum(sl0+sh0), s1=wave_sum(sl1+sh1);                   \
    const float s2=wave_sum(sl2+sh2), s3=wave_sum(sl3+sh3);                   \
    if(lane==0){                                                              \
      st3(op+r0g  , TAU*((ROWV?la[0]:lb2) - fmaf(sc,AF[0].w,flog2(s0))));     \
      st3(op+r0g+1, TAU*((ROWV?la[1]:lb2) - fmaf(sc,AF[1].w,flog2(s1))));     \
      st3(op+r0g+2, TAU*((ROWV?la[2]:lb2) - fmaf(sc,AF[2].w,flog2(s2))));     \
      st3(op+r0g+3, TAU*((ROWV?la[3]:lb2) - fmaf(sc,AF[3].w,flog2(s3))));     \
    }                                                                         \
    bbar(bbase, PH, blk);                                                     \
  }

__global__ __launch_bounds__(512,4) void k_fused(const float* __restrict__ x0,
                                                 const float* __restrict__ xgt,
                                                 const float* __restrict__ vp,
                                                 const float* __restrict__ ap,
                                                 const float* __restrict__ mxp,
                                                 float* __restrict__ ws,
                                                 float* __restrict__ out){
  __shared__ v2f sxA[1024], syA[1024], szA[1024], n2A[1024];   // A side SoA
  __shared__ v2f sxB[1024], syB[1024], szB[1024], n2B[1024];   // B side SoA
  __shared__ float sa32[32], sla[32], sal[32];
  __shared__ float sred[24], sfin[40];
  __shared__ int   sLast;
  const int blk = blockIdx.x, tid = threadIdx.x, lane = tid&63, wid = tid>>6;
  const int b = blk>>6, j = blk&63;               // batch, block-in-batch
  const int r0l = j*32 + (wid<<2);                // batch-local row of wave
  const int r0g = b*2048 + r0l;                   // global row
  unsigned* bbase = reinterpret_cast<unsigned*>(ws) + OFF_BBAR + b*512;

  // ---- local prep: load batch points raw (SoA pairs), alpha head ----
  for(int s=tid;s<1024;s+=512){
    const int gi = (b*2048 + 2*s)*3;
    const float xa0=x0[gi],  ya0=x0[gi+1], za0=x0[gi+2];
    const float xa1=x0[gi+3],ya1=x0[gi+4], za1=x0[gi+5];
    sxA[s]=(v2f){xa0,xa1}; syA[s]=(v2f){ya0,ya1}; szA[s]=(v2f){za0,za1};
    n2A[s]=(v2f){xa0*xa0+ya0*ya0+za0*za0, xa1*xa1+ya1*ya1+za1*za1};
    const float xb0=xgt[gi],  yb0=xgt[gi+1], zb0=xgt[gi+2];
    const float xb1=xgt[gi+3],yb1=xgt[gi+4], zb1=xgt[gi+5];
    sxB[s]=(v2f){xb0,xb1}; syB[s]=(v2f){yb0,yb1}; szB[s]=(v2f){zb0,zb1};
    n2B[s]=(v2f){xb0*xb0+yb0*yb0+zb0*zb0, xb1*xb1+yb1*yb1+zb1*zb1};
  }
  if(wid == 0){
    float a_=0.0f, w_=0.0f, se_=0.0f;
    if(lane < 32){
      const int row = b*2048 + j*32 + lane;
      const float al = ap[row];
      const float a = 1.0f/(1.0f + fexp2(-10.0f*tanhf(al*0.1f)*LOG2E));
      sa32[lane] = a;
      sla[lane]  = flog2(fmaxf(a,1e-30f));
      sal[lane]  = al;
      const float w = 1.0f/(1.0f + fexp2(-al*LOG2E));
      const float x = x0[row*3], y = x0[row*3+1], z = x0[row*3+2];
      const float tx = mxp[row*3]-x, ty = mxp[row*3+1]-y, tz = mxp[row*3+2]-z;
      const float dx = vp[row*3]-tx, dy = vp[row*3+1]-ty, dz = vp[row*3+2]-tz;
      a_ = a; w_ = w; se_ = (dx*dx+dy*dy+dz*dz)*w;
    }
    const float sa_s = wave_sum(a_), sw_s = wave_sum(w_), sew_s = wave_sum(se_);
    if(lane == 0){
      st3(ws+OFF_SUMAP+blk, sa_s);
      st3(ws+OFF_SWP  +blk, sw_s);
      st3(ws+OFF_SEWP +blk, sew_s);
    }
  }
  __syncthreads();

  // own-row fragments (RAW, persist across passes) + alpha registers
  const float* fxA = (const float*)sxA; const float* fyA = (const float*)syA;
  const float* fzA = (const float*)szA; const float* fnA = (const float*)n2A;
  const float* fxB = (const float*)sxB; const float* fyB = (const float*)syB;
  const float* fzB = (const float*)szB; const float* fnB = (const float*)n2B;
  float4 AR[4], AC[4]; float la[4], av[4], alv[4];
  #pragma unroll
  for(int r=0;r<4;r++){
    const int q = r0l + r;
    AR[r] = make_float4(fxA[q], fyA[q], fzA[q], fnA[q]);
    AC[r] = make_float4(fxB[q], fyB[q], fzB[q], fnB[q]);
    la[r] = sla[(wid<<2)+r]; av[r] = sa32[(wid<<2)+r]; alv[r] = sal[(wid<<2)+r];
  }

  // ---- phase 1: cmax (raw SoA; hoisted -2*row coeffs; +n2a at end) ----
  {
    const v2f h0x={-2*AR[0].x,-2*AR[0].x}, h0y={-2*AR[0].y,-2*AR[0].y}, h0z={-2*AR[0].z,-2*AR[0].z};
    const v2f h1x={-2*AR[1].x,-2*AR[1].x}, h1y={-2*AR[1].y,-2*AR[1].y}, h1z={-2*AR[1].z,-2*AR[1].z};
    const v2f h2x={-2*AR[2].x,-2*AR[2].x}, h2y={-2*AR[2].y,-2*AR[2].y}, h2z={-2*AR[2].z,-2*AR[2].z};
    const v2f h3x={-2*AR[3].x,-2*AR[3].x}, h3y={-2*AR[3].y,-2*AR[3].y}, h3z={-2*AR[3].z,-2*AR[3].z};
    float m0=-1e30f,m1=-1e30f,m2=-1e30f,m3=-1e30f;  // max of (n2b - 2 a.b)
    #pragma unroll 2
    for(int p=lane;p<1024;p+=64){
      const v2f xp=sxB[p], yp=syB[p], zp=szB[p], np=n2B[p];
      v2f c;
      c = vfma(h0x,xp,vfma(h0y,yp,vfma(h0z,zp,np))); m0=fmaxf(m0,fmaxf(c[0],c[1]));
      c = vfma(h1x,xp,vfma(h1y,yp,vfma(h1z,zp,np))); m1=fmaxf(m1,fmaxf(c[0],c[1]));
      c = vfma(h2x,xp,vfma(h2y,yp,vfma(h2z,zp,np))); m2=fmaxf(m2,fmaxf(c[0],c[1]));
      c = vfma(h3x,xp,vfma(h3y,yp,vfma(h3z,zp,np))); m3=fmaxf(m3,fmaxf(c[0],c[1]));
    }
    const float c0 = fmaxf(0.0f, AR[0].w + m0), c1 = fmaxf(0.0f, AR[1].w + m1);
    const float c2 = fmaxf(0.0f, AR[2].w + m2), c3 = fmaxf(0.0f, AR[3].w + m3);
    const float cmv = wave_max(fmaxf(fmaxf(c0,c1),fmaxf(c2,c3)));
    if(lane==0) sred[wid] = cmv;
    __syncthreads();
    if(tid==0){
      float m = sred[0];
      #pragma unroll
      for(int i=1;i<8;i++) m = fmaxf(m, sred[i]);
      st3(ws+OFF_CPART+blk, m);
    }
  }
  bbar(bbase, 1, blk);

  // ---- per-batch constants (lane indexes the batch's 64 block partials) ----
  const float cm = wave_max(ld3(ws+OFF_CPART + b*64 + lane));
  const float sc = NEG20LOG2E/(cm + 1e-8f);
  const float n2sc = -2.0f*sc;
  const float sav = wave_sum(ld3(ws+OFF_SUMAP + b*64 + lane));
  const float lb2 = flog2(fmaxf(sav*(1.0f/2048.0f), 1e-30f));

  // ---- rescale LDS SoA in place (xyz *= n2sc, n2 *= sc) ----
  {
    const v2f vs = {n2sc, n2sc}, vc = {sc, sc};
    for(int s=tid;s<1024;s+=512){
      sxA[s]*=vs; syA[s]*=vs; szA[s]*=vs; n2A[s]*=vc;
      sxB[s]*=vs; syB[s]*=vs; szB[s]*=vs; n2B[s]*=vc;
    }
  }
  __syncthreads();

  // ---- phases 2..11: 5 Sinkhorn iterations (row, col), per-batch sync ----
  LSE_PASS(true,  true,  2)
  LSE_PASS(false, false, 3)
  LSE_PASS(true,  false, 4)
  LSE_PASS(false, false, 5)
  LSE_PASS(true,  false, 6)
  LSE_PASS(false, false, 7)
  LSE_PASS(true,  false, 8)
  LSE_PASS(false, false, 9)
  LSE_PASS(true,  false, 10)
  LSE_PASS(false, false, 11)

  // ---- final pi pass: register lv; S, Q=Σp·arg, L=Σp·lv per row ----
  {
    float* lv = ws + OFF_LV + 2048*b;
    v2f pot[16];
    #pragma unroll
    for(int i=0;i<16;i++) pot[i] = ld3x2(lv + 2*(lane + (i<<6)));
    const v2f ax0={AR[0].x,AR[0].x}, ay0={AR[0].y,AR[0].y}, az0={AR[0].z,AR[0].z};
    const v2f ax1={AR[1].x,AR[1].x}, ay1={AR[1].y,AR[1].y}, az1={AR[1].z,AR[1].z};
    const v2f ax2={AR[2].x,AR[2].x}, ay2={AR[2].y,AR[2].y}, az2={AR[2].z,AR[2].z};
    const v2f ax3={AR[3].x,AR[3].x}, ay3={AR[3].y,AR[3].y}, az3={AR[3].z,AR[3].z};
    float S[4]={0,0,0,0}, Q[4]={0,0,0,0}, L[4]={0,0,0,0};
    #pragma unroll
    for(int i=0;i<16;i++){
      const int p = lane + (i<<6);
      const v2f xp=sxB[p], yp=syB[p], zp=szB[p];
      const v2f lvp = pot[i];
      const v2f wp = n2B[p] + lvp;
      v2f c; float e0, e1;
      c = vfma(ax0,xp,vfma(ay0,yp,vfma(az0,zp,wp)));
      e0=fexp2(c[0]); e1=fexp2(c[1]);
      S[0]+=e0+e1; Q[0]=fmaf(e0,c[0],fmaf(e1,c[1],Q[0]));
      L[0]=fmaf(e0,lvp[0],fmaf(e1,lvp[1],L[0]));
      c = vfma(ax1,xp,vfma(ay1,yp,vfma(az1,zp,wp)));
      e0=fexp2(c[0]); e1=fexp2(c[1]);
      S[1]+=e0+e1; Q[1]=fmaf(e0,c[0],fmaf(e1,c[1],Q[1]));
      L[1]=fmaf(e0,lvp[0],fmaf(e1,lvp[1],L[1]));
      c = vfma(ax2,xp,vfma(ay2,yp,vfma(az2,zp,wp)));
      e0=fexp2(c[0]); e1=fexp2(c[1]);
      S[2]+=e0+e1; Q[2]=fmaf(e0,c[0],fmaf(e1,c[1],Q[2]));
      L[2]=fmaf(e0,lvp[0],fmaf(e1,lvp[1],L[2]));
      c = vfma(ax3,xp,vfma(ay3,yp,vfma(az3,zp,wp)));
      e0=fexp2(c[0]); e1=fexp2(c[1]);
      S[3]+=e0+e1; Q[3]=fmaf(e0,c[0],fmaf(e1,c[1],Q[3]));
      L[3]=fmaf(e0,lvp[0],fmaf(e1,lvp[1],L[3]));
    }
    float spc = 0.0f, bce = 0.0f, spt = 0.0f;
    #pragma unroll
    for(int r=0;r<4;r++){
      const float St = wave_sum(S[r]);
      const float Qt = wave_sum(Q[r]);
      const float Lt = wave_sum(L[r]);
      const float lur = ld3(ws+OFF_LU+r0g+r);
      const float cr = fmaf(sc, AR[r].w, lur);   // hoisted row constant
      const float p2 = fexp2(cr);
      const float sp = p2*St;                    // true row sum of pi
      // sum(pi*arg_true) = p2*(Q + cr*S); klog = arg_true - lu - lv
      spc += p2*fmaf(cr,St,Qt) - p2*Lt - lur*sp;
      float yv = sp / (av[r] + 1e-8f);
      yv = fminf(fmaxf(yv,0.0f),1.0f);
      const float al = alv[r];
      bce += fmaxf(al,0.0f) - al*yv
           + 0.69314718056f*flog2(1.0f + fexp2(-fabsf(al)*LOG2E));
      spt += sp;
    }
    if(lane==0){ sred[wid]=bce; sred[8+wid]=spt; sred[16+wid]=spc; }
    __syncthreads();
    if(tid==0){
      float tb=0, ts=0, tc=0;
      #pragma unroll
      for(int i=0;i<8;i++){ tb+=sred[i]; ts+=sred[8+i]; tc+=sred[16+i]; }
      st3(ws+OFF_FPART +        blk, tb);
      st3(ws+OFF_FPART + 512  + blk, ts);
      st3(ws+OFF_FPART + 1024 + blk, tc);
    }
  }

  // ---- last-block-done combine (tail counter, no global barrier) ----
  __syncthreads();
  if(tid == 0){
    asm volatile("s_waitcnt vmcnt(0)" ::: "memory");  // FPART at L3
    unsigned* tail = reinterpret_cast<unsigned*>(ws) + OFF_TAIL;
    const unsigned v = __hip_atomic_fetch_add(tail, 1u, __ATOMIC_RELAXED,
                                              __HIP_MEMORY_SCOPE_AGENT);
    sLast = (v == 511u) ? 1 : 0;
  }
  __syncthreads();
  if(sLast){
    float pb = ld3(ws+OFF_FPART+tid);
    float ps = ld3(ws+OFF_FPART+512+tid);
    float pc = ld3(ws+OFF_FPART+1024+tid);
    float pw = ld3(ws+OFF_SWP+tid);
    float pe = ld3(ws+OFF_SEWP+tid);
    pb=wave_sum(pb); ps=wave_sum(ps); pc=wave_sum(pc);
    pw=wave_sum(pw); pe=wave_sum(pe);
    if(lane==0){
      sfin[wid*5+0]=pb; sfin[wid*5+1]=ps; sfin[wid*5+2]=pc;
      sfin[wid*5+3]=pw; sfin[wid*5+4]=pe;
    }
    __syncthreads();
    if(tid==0){
      float bce=0, sp=0, spc=0, sw=0, sew=0;
      #pragma unroll
      for(int w=0;w<8;w++){
        bce+=sfin[w*5+0]; sp+=sfin[w*5+1]; spc+=sfin[w*5+2];
        sw +=sfin[w*5+3]; sew+=sfin[w*5+4];
      }
      const float loss_vel  = sew / fmaxf(sw, 1.0f);
      const float loss_surv = bce / 16384.0f;
      // sum(pi*cost_n) = spc * (-ln2/20)  since klog = -20*log2e*cost_n
      const float loss_tr = (spc * (-0.03465735902799726f)) / fmaxf(sp, 1e-8f);
      out[0] = loss_vel + loss_surv + 0.1f*loss_tr;
    }
  }
}

extern "C" void kernel_launch(void* const* d_in, const int* in_sizes, int n_in,
                              void* d_out, int out_size, void* d_ws, size_t ws_size,
                              hipStream_t stream) {
  (void)in_sizes; (void)n_in; (void)out_size; (void)ws_size;
  const float* x0  = (const float*)d_in[0];
  const float* xgt = (const float*)d_in[1];
  const float* vp  = (const float*)d_in[2];
  const float* ap  = (const float*)d_in[3];
  const float* mxp = (const float*)d_in[5];   // t (d_in[4]) unused
  float* ws  = (float*)d_ws;
  float* out = (float*)d_out;

  k_init<<<1, 256, 0, stream>>>(ws);          // zero barrier words + tail ctr

  k_fused<<<512, 512, 0, stream>>>(x0, xgt, vp, ap, mxp, ws, out);
}

// Round 17
// 115.976 us; speedup vs baseline: 1.1619x; 1.1619x over previous
//
#include <hip/hip_runtime.h>
#include <math.h>

// FlowMatchingLoss: B=8, M=K=2048. Log-domain pre-scaled by log2e (hw exp2/log2).
//   K_log' = sc_b * c,  sc_b = -20*log2e/(cmax_b+1e-8)
// Round-17: register potentials, PRESSURE-BOUNDED. R16's pot[16] (32 VGPR,
// all loads in flight) spilled to scratch (WRITE_SIZE 5.4->69MB). Fix:
// software-pipelined chunks of 4 pairs, double-buffered (potA/potB = 16 VGPR
// transient); prefetch chunk c+1 while computing chunk c (64 exp2 covers L3
// latency); sched_barrier(0) per chunk stops the scheduler re-hoisting all
// loads (R16's failure). Epilogue scalars (la/a/alpha) read from LDS at use
// instead of living in registers. No per-pass LDS staging, no swf array.
// Kept from R15: k-pair SoA LDS + loop-invariant row broadcasts, per-batch
// fence-free barriers, relaxed-agent L3 routing, tail-counter combine.

#define LOG2E 1.4426950408889634f
#define TAU   0.95238095238095238f     // 1/(1+0.05)
#define NEG20LOG2E (-28.853900817779268f)

typedef float v2f __attribute__((ext_vector_type(2)));

// workspace layout, 4-byte units
enum : int {
  OFF_LU    = 0,        // 16384: log_u * log2e   (L3-resident via atomics)
  OFF_LV    = 16384,    // 16384: log_v * log2e
  OFF_CPART = 32768,    // 512 per-block cmax partials (64/batch)
  OFF_SUMAP = 33280,    // 512 per-block sum(a) partials (64/batch)
  OFF_SWP   = 33792,    // 512 per-block sum(w)
  OFF_SEWP  = 34304,    // 512 per-block sum(w*err)
  OFF_FPART = 34816,    // 3*512 final partials (bce, sum_pi, sum_pi*klog)
  OFF_BBAR  = 36352,    // 8 batches x 512: [0..3]*32 arr | 4*32 root | (8+g)*32 rel
  OFF_TAIL  = 40448,    // last-block-done counter (padded slot)
  OFF_END   = 40480
};

__device__ __forceinline__ float fexp2(float x){ return __builtin_amdgcn_exp2f(x); }
__device__ __forceinline__ float flog2(float x){ return __builtin_amdgcn_logf(x); }
__device__ __forceinline__ v2f vfma(v2f a, v2f b, v2f c){
  return __builtin_elementwise_fma(a,b,c);
}

// L3-coherent access (relaxed agent atomics: cache-bypass, no maintenance)
__device__ __forceinline__ float ld3(const float* p){
  return __hip_atomic_load(p, __ATOMIC_RELAXED, __HIP_MEMORY_SCOPE_AGENT);
}
__device__ __forceinline__ v2f ld3x2(const float* p){   // 8B-aligned pair
  const unsigned long long u =
      __hip_atomic_load(reinterpret_cast<const unsigned long long*>(p),
                        __ATOMIC_RELAXED, __HIP_MEMORY_SCOPE_AGENT);
  return __builtin_bit_cast(v2f, u);
}
__device__ __forceinline__ void st3(float* p, float v){
  __hip_atomic_store(p, v, __ATOMIC_RELAXED, __HIP_MEMORY_SCOPE_AGENT);
}

__device__ __forceinline__ float wave_sum(float v){
  #pragma unroll
  for(int m=32;m;m>>=1) v += __shfl_xor(v,m,64);
  return v;
}
__device__ __forceinline__ float wave_max(float v){
  #pragma unroll
  for(int m=32;m;m>>=1) v = fmaxf(v,__shfl_xor(v,m,64));
  return v;
}

// per-batch fence-free barrier: 64 blocks, 4 groups of 16 -> root ->
// 4 release flags; leaders spin on own group's flag (16 pollers/line).
__device__ __forceinline__ void bbar(unsigned* bbase, int phase, int blk){
  __syncthreads();
  if(threadIdx.x == 0){
    asm volatile("s_waitcnt vmcnt(0)" ::: "memory");   // stores reached L3
    const int g = (blk>>4)&3;
    unsigned* garr = bbase + g*32;
    unsigned* root = bbase + 4*32;
    unsigned* grel = bbase + (8+g)*32;
    const unsigned va = __hip_atomic_fetch_add(garr, 1u, __ATOMIC_RELAXED,
                                               __HIP_MEMORY_SCOPE_AGENT);
    if(va == (unsigned)(16*phase - 1)){
      const unsigned vr = __hip_atomic_fetch_add(root, 1u, __ATOMIC_RELAXED,
                                                 __HIP_MEMORY_SCOPE_AGENT);
      if(vr == (unsigned)(4*phase - 1)){
        #pragma unroll
        for(int g2=0; g2<4; ++g2)
          __hip_atomic_store(bbase + (8+g2)*32, (unsigned)phase,
                             __ATOMIC_RELAXED, __HIP_MEMORY_SCOPE_AGENT);
      }
    }
    while(__hip_atomic_load(grel, __ATOMIC_RELAXED, __HIP_MEMORY_SCOPE_AGENT)
          < (unsigned)phase)
      __builtin_amdgcn_s_sleep(1);
    asm volatile("" ::: "memory");
  }
  __syncthreads();
}

__global__ __launch_bounds__(256) void k_init(float* ws){
  unsigned* bar = reinterpret_cast<unsigned*>(ws);
  for(int i=threadIdx.x; i<OFF_END-OFF_BBAR; i+=256) bar[OFF_BBAR+i] = 0u;
}

// one lse half-iteration, k-pair SoA + chunked register potentials.
// Iterated side in LDS scaled (xyz=n2sc*xyz pairs, n2=sc*|.|^2 pairs).
// 4 chunks x 4 pairs; prefetch chunk c+1 into potB while computing chunk c
// from potA; sched_barrier(0) pins the pipeline (prevents load re-hoist).
template<bool ROWV, bool FIRSTV>
__device__ __forceinline__ void lse_pass(
    const v2f* SX, const v2f* SY, const v2f* SZ, const v2f* SN,
    const float4* AF, const float* lo, float* op, int r0g,
    const float* slaW, float lb2, float sc, int lane)
{
  v2f potA[4], potB[4];
  if(!FIRSTV){
    #pragma unroll
    for(int j=0;j<4;j++) potA[j] = ld3x2(lo + 2*(lane + (j<<6)));
  }
  const v2f ax0={AF[0].x,AF[0].x}, ay0={AF[0].y,AF[0].y}, az0={AF[0].z,AF[0].z};
  const v2f ax1={AF[1].x,AF[1].x}, ay1={AF[1].y,AF[1].y}, az1={AF[1].z,AF[1].z};
  const v2f ax2={AF[2].x,AF[2].x}, ay2={AF[2].y,AF[2].y}, az2={AF[2].z,AF[2].z};
  const v2f ax3={AF[3].x,AF[3].x}, ay3={AF[3].y,AF[3].y}, az3={AF[3].z,AF[3].z};
  float sl0=0,sh0=0,sl1=0,sh1=0,sl2=0,sh2=0,sl3=0,sh3=0;
  #pragma unroll
  for(int cc=0; cc<4; ++cc){
    if(!FIRSTV && cc<3){
      #pragma unroll
      for(int j=0;j<4;j++)
        potB[j] = ld3x2(lo + 2*(lane + ((((cc+1)<<2)+j)<<6)));
    }
    #pragma unroll
    for(int j=0;j<4;j++){
      const int p = lane + (((cc<<2)+j)<<6);
      const v2f xp=SX[p], yp=SY[p], zp=SZ[p];
      const v2f wp = FIRSTV ? SN[p] : (SN[p] + potA[j]);
      v2f c;
      c = vfma(ax0,xp,vfma(ay0,yp,vfma(az0,zp,wp)));
      sl0 += fexp2(c[0]); sh0 += fexp2(c[1]);
      c = vfma(ax1,xp,vfma(ay1,yp,vfma(az1,zp,wp)));
      sl1 += fexp2(c[0]); sh1 += fexp2(c[1]);
      c = vfma(ax2,xp,vfma(ay2,yp,vfma(az2,zp,wp)));
      sl2 += fexp2(c[0]); sh2 += fexp2(c[1]);
      c = vfma(ax3,xp,vfma(ay3,yp,vfma(az3,zp,wp)));
      sl3 += fexp2(c[0]); sh3 += fexp2(c[1]);
    }
    if(!FIRSTV){
      __builtin_amdgcn_sched_barrier(0);   // pin pipeline; cap live loads
      if(cc<3){
        #pragma unroll
        for(int j=0;j<4;j++) potA[j] = potB[j];
      }
    }
  }
  const float s0=wave_sum(sl0+sh0), s1=wave_sum(sl1+sh1);
  const float s2=wave_sum(sl2+sh2), s3=wave_sum(sl3+sh3);
  if(lane==0){
    st3(op+r0g  , TAU*((ROWV?slaW[0]:lb2) - fmaf(sc,AF[0].w,flog2(s0))));
    st3(op+r0g+1, TAU*((ROWV?slaW[1]:lb2) - fmaf(sc,AF[1].w,flog2(s1))));
    st3(op+r0g+2, TAU*((ROWV?slaW[2]:lb2) - fmaf(sc,AF[2].w,flog2(s2))));
    st3(op+r0g+3, TAU*((ROWV?slaW[3]:lb2) - fmaf(sc,AF[3].w,flog2(s3))));
  }
}

__global__ __launch_bounds__(512,4) void k_fused(const float* __restrict__ x0,
                                                 const float* __restrict__ xgt,
                                                 const float* __restrict__ vp,
                                                 const float* __restrict__ ap,
                                                 const float* __restrict__ mxp,
                                                 float* __restrict__ ws,
                                                 float* __restrict__ out){
  __shared__ v2f sxA[1024], syA[1024], szA[1024], n2A[1024];   // A side SoA
  __shared__ v2f sxB[1024], syB[1024], szB[1024], n2B[1024];   // B side SoA
  __shared__ float sa32[32], sla[32], sal[32];
  __shared__ float sred[24], sfin[40];
  __shared__ int   sLast;
  const int blk = blockIdx.x, tid = threadIdx.x, lane = tid&63, wid = tid>>6;
  const int b = blk>>6, j = blk&63;               // batch, block-in-batch
  const int r0l = j*32 + (wid<<2);                // batch-local row of wave
  const int r0g = b*2048 + r0l;                   // global row
  unsigned* bbase = reinterpret_cast<unsigned*>(ws) + OFF_BBAR + b*512;

  // ---- local prep: load batch points raw (SoA pairs), alpha head ----
  for(int s=tid;s<1024;s+=512){
    const int gi = (b*2048 + 2*s)*3;
    const float xa0=x0[gi],  ya0=x0[gi+1], za0=x0[gi+2];
    const float xa1=x0[gi+3],ya1=x0[gi+4], za1=x0[gi+5];
    sxA[s]=(v2f){xa0,xa1}; syA[s]=(v2f){ya0,ya1}; szA[s]=(v2f){za0,za1};
    n2A[s]=(v2f){xa0*xa0+ya0*ya0+za0*za0, xa1*xa1+ya1*ya1+za1*za1};
    const float xb0=xgt[gi],  yb0=xgt[gi+1], zb0=xgt[gi+2];
    const float xb1=xgt[gi+3],yb1=xgt[gi+4], zb1=xgt[gi+5];
    sxB[s]=(v2f){xb0,xb1}; syB[s]=(v2f){yb0,yb1}; szB[s]=(v2f){zb0,zb1};
    n2B[s]=(v2f){xb0*xb0+yb0*yb0+zb0*zb0, xb1*xb1+yb1*yb1+zb1*zb1};
  }
  if(wid == 0){
    float a_=0.0f, w_=0.0f, se_=0.0f;
    if(lane < 32){
      const int row = b*2048 + j*32 + lane;
      const float al = ap[row];
      const float a = 1.0f/(1.0f + fexp2(-10.0f*tanhf(al*0.1f)*LOG2E));
      sa32[lane] = a;
      sla[lane]  = flog2(fmaxf(a,1e-30f));
      sal[lane]  = al;
      const float w = 1.0f/(1.0f + fexp2(-al*LOG2E));
      const float x = x0[row*3], y = x0[row*3+1], z = x0[row*3+2];
      const float tx = mxp[row*3]-x, ty = mxp[row*3+1]-y, tz = mxp[row*3+2]-z;
      const float dx = vp[row*3]-tx, dy = vp[row*3+1]-ty, dz = vp[row*3+2]-tz;
      a_ = a; w_ = w; se_ = (dx*dx+dy*dy+dz*dz)*w;
    }
    const float sa_s = wave_sum(a_), sw_s = wave_sum(w_), sew_s = wave_sum(se_);
    if(lane == 0){
      st3(ws+OFF_SUMAP+blk, sa_s);
      st3(ws+OFF_SWP  +blk, sw_s);
      st3(ws+OFF_SEWP +blk, sew_s);
    }
  }
  __syncthreads();

  // own-row fragments (RAW, persist across passes)
  const float* fxA = (const float*)sxA; const float* fyA = (const float*)syA;
  const float* fzA = (const float*)szA; const float* fnA = (const float*)n2A;
  const float* fxB = (const float*)sxB; const float* fyB = (const float*)syB;
  const float* fzB = (const float*)szB; const float* fnB = (const float*)n2B;
  float4 AR[4], AC[4];
  #pragma unroll
  for(int r=0;r<4;r++){
    const int q = r0l + r;
    AR[r] = make_float4(fxA[q], fyA[q], fzA[q], fnA[q]);
    AC[r] = make_float4(fxB[q], fyB[q], fzB[q], fnB[q]);
  }
  const float* slaW = &sla[(wid<<2)];

  // ---- phase 1: cmax (raw SoA; hoisted -2*row coeffs; +n2a at end) ----
  {
    const v2f h0x={-2*AR[0].x,-2*AR[0].x}, h0y={-2*AR[0].y,-2*AR[0].y}, h0z={-2*AR[0].z,-2*AR[0].z};
    const v2f h1x={-2*AR[1].x,-2*AR[1].x}, h1y={-2*AR[1].y,-2*AR[1].y}, h1z={-2*AR[1].z,-2*AR[1].z};
    const v2f h2x={-2*AR[2].x,-2*AR[2].x}, h2y={-2*AR[2].y,-2*AR[2].y}, h2z={-2*AR[2].z,-2*AR[2].z};
    const v2f h3x={-2*AR[3].x,-2*AR[3].x}, h3y={-2*AR[3].y,-2*AR[3].y}, h3z={-2*AR[3].z,-2*AR[3].z};
    float m0=-1e30f,m1=-1e30f,m2=-1e30f,m3=-1e30f;  // max of (n2b - 2 a.b)
    #pragma unroll 2
    for(int p=lane;p<1024;p+=64){
      const v2f xp=sxB[p], yp=syB[p], zp=szB[p], np=n2B[p];
      v2f c;
      c = vfma(h0x,xp,vfma(h0y,yp,vfma(h0z,zp,np))); m0=fmaxf(m0,fmaxf(c[0],c[1]));
      c = vfma(h1x,xp,vfma(h1y,yp,vfma(h1z,zp,np))); m1=fmaxf(m1,fmaxf(c[0],c[1]));
      c = vfma(h2x,xp,vfma(h2y,yp,vfma(h2z,zp,np))); m2=fmaxf(m2,fmaxf(c[0],c[1]));
      c = vfma(h3x,xp,vfma(h3y,yp,vfma(h3z,zp,np))); m3=fmaxf(m3,fmaxf(c[0],c[1]));
    }
    const float c0 = fmaxf(0.0f, AR[0].w + m0), c1 = fmaxf(0.0f, AR[1].w + m1);
    const float c2 = fmaxf(0.0f, AR[2].w + m2), c3 = fmaxf(0.0f, AR[3].w + m3);
    const float cmv = wave_max(fmaxf(fmaxf(c0,c1),fmaxf(c2,c3)));
    if(lane==0) sred[wid] = cmv;
    __syncthreads();
    if(tid==0){
      float m = sred[0];
      #pragma unroll
      for(int i=1;i<8;i++) m = fmaxf(m, sred[i]);
      st3(ws+OFF_CPART+blk, m);
    }
  }
  bbar(bbase, 1, blk);

  // ---- per-batch constants (lane indexes the batch's 64 block partials) ----
  const float cm = wave_max(ld3(ws+OFF_CPART + b*64 + lane));
  const float sc = NEG20LOG2E/(cm + 1e-8f);
  const float n2sc = -2.0f*sc;
  const float sav = wave_sum(ld3(ws+OFF_SUMAP + b*64 + lane));
  const float lb2 = flog2(fmaxf(sav*(1.0f/2048.0f), 1e-30f));

  // ---- rescale LDS SoA in place (xyz *= n2sc, n2 *= sc) ----
  {
    const v2f vs = {n2sc, n2sc}, vc = {sc, sc};
    for(int s=tid;s<1024;s+=512){
      sxA[s]*=vs; syA[s]*=vs; szA[s]*=vs; n2A[s]*=vc;
      sxB[s]*=vs; syB[s]*=vs; szB[s]*=vs; n2B[s]*=vc;
    }
  }
  __syncthreads();

  // ---- phases 2..11: 5 Sinkhorn iterations (row, col), per-batch sync ----
  float* LU = ws + OFF_LU + 2048*b;
  float* LV = ws + OFF_LV + 2048*b;
  float* LUo = ws + OFF_LU;
  float* LVo = ws + OFF_LV;
  lse_pass<true ,true >(sxB,syB,szB,n2B,AR,LV,LUo,r0g,slaW,lb2,sc,lane);
  bbar(bbase, 2, blk);
  lse_pass<false,false>(sxA,syA,szA,n2A,AC,LU,LVo,r0g,slaW,lb2,sc,lane);
  bbar(bbase, 3, blk);
  lse_pass<true ,false>(sxB,syB,szB,n2B,AR,LV,LUo,r0g,slaW,lb2,sc,lane);
  bbar(bbase, 4, blk);
  lse_pass<false,false>(sxA,syA,szA,n2A,AC,LU,LVo,r0g,slaW,lb2,sc,lane);
  bbar(bbase, 5, blk);
  lse_pass<true ,false>(sxB,syB,szB,n2B,AR,LV,LUo,r0g,slaW,lb2,sc,lane);
  bbar(bbase, 6, blk);
  lse_pass<false,false>(sxA,syA,szA,n2A,AC,LU,LVo,r0g,slaW,lb2,sc,lane);
  bbar(bbase, 7, blk);
  lse_pass<true ,false>(sxB,syB,szB,n2B,AR,LV,LUo,r0g,slaW,lb2,sc,lane);
  bbar(bbase, 8, blk);
  lse_pass<false,false>(sxA,syA,szA,n2A,AC,LU,LVo,r0g,slaW,lb2,sc,lane);
  bbar(bbase, 9, blk);
  lse_pass<true ,false>(sxB,syB,szB,n2B,AR,LV,LUo,r0g,slaW,lb2,sc,lane);
  bbar(bbase, 10, blk);
  lse_pass<false,false>(sxA,syA,szA,n2A,AC,LU,LVo,r0g,slaW,lb2,sc,lane);
  bbar(bbase, 11, blk);

  // ---- final pi pass: chunked register lv; S, Q=Σp·arg, L=Σp·lv per row ----
  {
    v2f potA[4], potB[4];
    #pragma unroll
    for(int jj=0;jj<4;jj++) potA[jj] = ld3x2(LV + 2*(lane + (jj<<6)));
    const v2f ax0={AR[0].x,AR[0].x}, ay0={AR[0].y,AR[0].y}, az0={AR[0].z,AR[0].z};
    const v2f ax1={AR[1].x,AR[1].x}, ay1={AR[1].y,AR[1].y}, az1={AR[1].z,AR[1].z};
    const v2f ax2={AR[2].x,AR[2].x}, ay2={AR[2].y,AR[2].y}, az2={AR[2].z,AR[2].z};
    const v2f ax3={AR[3].x,AR[3].x}, ay3={AR[3].y,AR[3].y}, az3={AR[3].z,AR[3].z};
    float S[4]={0,0,0,0}, Q[4]={0,0,0,0}, L[4]={0,0,0,0};
    #pragma unroll
    for(int cc=0; cc<4; ++cc){
      if(cc<3){
        #pragma unroll
        for(int jj=0;jj<4;jj++)
          potB[jj] = ld3x2(LV + 2*(lane + ((((cc+1)<<2)+jj)<<6)));
      }
      #pragma unroll
      for(int jj=0;jj<4;jj++){
        const int p = lane + (((cc<<2)+jj)<<6);
        const v2f xp=sxB[p], yp=syB[p], zp=szB[p];
        const v2f lvp = potA[jj];
        const v2f wp = n2B[p] + lvp;
        v2f c; float e0, e1;
        c = vfma(ax0,xp,vfma(ay0,yp,vfma(az0,zp,wp)));
        e0=fexp2(c[0]); e1=fexp2(c[1]);
        S[0]+=e0+e1; Q[0]=fmaf(e0,c[0],fmaf(e1,c[1],Q[0]));
        L[0]=fmaf(e0,lvp[0],fmaf(e1,lvp[1],L[0]));
        c = vfma(ax1,xp,vfma(ay1,yp,vfma(az1,zp,wp)));
        e0=fexp2(c[0]); e1=fexp2(c[1]);
        S[1]+=e0+e1; Q[1]=fmaf(e0,c[0],fmaf(e1,c[1],Q[1]));
        L[1]=fmaf(e0,lvp[0],fmaf(e1,lvp[1],L[1]));
        c = vfma(ax2,xp,vfma(ay2,yp,vfma(az2,zp,wp)));
        e0=fexp2(c[0]); e1=fexp2(c[1]);
        S[2]+=e0+e1; Q[2]=fmaf(e0,c[0],fmaf(e1,c[1],Q[2]));
        L[2]=fmaf(e0,lvp[0],fmaf(e1,lvp[1],L[2]));
        c = vfma(ax3,xp,vfma(ay3,yp,vfma(az3,zp,wp)));
        e0=fexp2(c[0]); e1=fexp2(c[1]);
        S[3]+=e0+e1; Q[3]=fmaf(e0,c[0],fmaf(e1,c[1],Q[3]));
        L[3]=fmaf(e0,lvp[0],fmaf(e1,lvp[1],L[3]));
      }
      __builtin_amdgcn_sched_barrier(0);
      if(cc<3){
        #pragma unroll
        for(int jj=0;jj<4;jj++) potA[jj] = potB[jj];
      }
    }
    float spc = 0.0f, bce = 0.0f, spt = 0.0f;
    #pragma unroll
    for(int r=0;r<4;r++){
      const float St = wave_sum(S[r]);
      const float Qt = wave_sum(Q[r]);
      const float Lt = wave_sum(L[r]);
      const float lur = ld3(ws+OFF_LU+r0g+r);
      const float cr = fmaf(sc, AR[r].w, lur);   // hoisted row constant
      const float p2 = fexp2(cr);
      const float sp = p2*St;                    // true row sum of pi
      // sum(pi*arg_true) = p2*(Q + cr*S); klog = arg_true - lu - lv
      spc += p2*fmaf(cr,St,Qt) - p2*Lt - lur*sp;
      float yv = sp / (sa32[(wid<<2)+r] + 1e-8f);
      yv = fminf(fmaxf(yv,0.0f),1.0f);
      const float al = sal[(wid<<2)+r];
      bce += fmaxf(al,0.0f) - al*yv
           + 0.69314718056f*flog2(1.0f + fexp2(-fabsf(al)*LOG2E));
      spt += sp;
    }
    if(lane==0){ sred[wid]=bce; sred[8+wid]=spt; sred[16+wid]=spc; }
    __syncthreads();
    if(tid==0){
      float tb=0, ts=0, tc=0;
      #pragma unroll
      for(int i=0;i<8;i++){ tb+=sred[i]; ts+=sred[8+i]; tc+=sred[16+i]; }
      st3(ws+OFF_FPART +        blk, tb);
      st3(ws+OFF_FPART + 512  + blk, ts);
      st3(ws+OFF_FPART + 1024 + blk, tc);
    }
  }

  // ---- last-block-done combine (tail counter, no global barrier) ----
  __syncthreads();
  if(tid == 0){
    asm volatile("s_waitcnt vmcnt(0)" ::: "memory");  // FPART at L3
    unsigned* tail = reinterpret_cast<unsigned*>(ws) + OFF_TAIL;
    const unsigned v = __hip_atomic_fetch_add(tail, 1u, __ATOMIC_RELAXED,
                                              __HIP_MEMORY_SCOPE_AGENT);
    sLast = (v == 511u) ? 1 : 0;
  }
  __syncthreads();
  if(sLast){
    float pb = ld3(ws+OFF_FPART+tid);
    float ps = ld3(ws+OFF_FPART+512+tid);
    float pc = ld3(ws+OFF_FPART+1024+tid);
    float pw = ld3(ws+OFF_SWP+tid);
    float pe = ld3(ws+OFF_SEWP+tid);
    pb=wave_sum(pb); ps=wave_sum(ps); pc=wave_sum(pc);
    pw=wave_sum(pw); pe=wave_sum(pe);
    if(lane==0){
      sfin[wid*5+0]=pb; sfin[wid*5+1]=ps; sfin[wid*5+2]=pc;
      sfin[wid*5+3]=pw; sfin[wid*5+4]=pe;
    }
    __syncthreads();
    if(tid==0){
      float bce=0, sp=0, spc=0, sw=0, sew=0;
      #pragma unroll
      for(int w=0;w<8;w++){
        bce+=sfin[w*5+0]; sp+=sfin[w*5+1]; spc+=sfin[w*5+2];
        sw +=sfin[w*5+3]; sew+=sfin[w*5+4];
      }
      const float loss_vel  = sew / fmaxf(sw, 1.0f);
      const float loss_surv = bce / 16384.0f;
      // sum(pi*cost_n) = spc * (-ln2/20)  since klog = -20*log2e*cost_n
      const float loss_tr = (spc * (-0.03465735902799726f)) / fmaxf(sp, 1e-8f);
      out[0] = loss_vel + loss_surv + 0.1f*loss_tr;
    }
  }
}

extern "C" void kernel_launch(void* const* d_in, const int* in_sizes, int n_in,
                              void* d_out, int out_size, void* d_ws, size_t ws_size,
                              hipStream_t stream) {
  (void)in_sizes; (void)n_in; (void)out_size; (void)ws_size;
  const float* x0  = (const float*)d_in[0];
  const float* xgt = (const float*)d_in[1];
  const float* vp  = (const float*)d_in[2];
  const float* ap  = (const float*)d_in[3];
  const float* mxp = (const float*)d_in[5];   // t (d_in[4]) unused
  float* ws  = (float*)d_ws;
  float* out = (float*)d_out;

  k_init<<<1, 256, 0, stream>>>(ws);          // zero barrier words + tail ctr

  k_fused<<<512, 512, 0, stream>>>(x0, xgt, vp, ap, mxp, ws, out);
}

// Round 18
// 99.425 us; speedup vs baseline: 1.3553x; 1.1665x over previous
//
#include <hip/hip_runtime.h>
#include <math.h>

// FlowMatchingLoss: B=8, M=K=2048. Log-domain pre-scaled by log2e (hw exp2/log2).
//   K_log' = sc_b * c,  sc_b = -20*log2e/(cmax_b+1e-8)
// Round-18: revert to R15 (best: 100.5us, VGPR 64, zero spill -- R16/R17's
// register-resident potentials spilled to scratch at any buffering depth).
// Two pressure-neutral deltas: (1) staging potential loads as single 8B
// ld3x2 (was 2x scalar ld3); (2) FIRST pass reads n2 pairs directly (no
// copy loop / no extra sync). Everything else identical to R15: k-pair SoA
// LDS with loop-invariant row broadcasts, per-batch fence-free barriers,
// relaxed-agent L3 routing, persistent scaled LDS points, tail combine.

#define LOG2E 1.4426950408889634f
#define TAU   0.95238095238095238f     // 1/(1+0.05)
#define NEG20LOG2E (-28.853900817779268f)

typedef float v2f __attribute__((ext_vector_type(2)));

// workspace layout, 4-byte units
enum : int {
  OFF_LU    = 0,        // 16384: log_u * log2e   (L3-resident via atomics)
  OFF_LV    = 16384,    // 16384: log_v * log2e
  OFF_CPART = 32768,    // 512 per-block cmax partials (64/batch)
  OFF_SUMAP = 33280,    // 512 per-block sum(a) partials (64/batch)
  OFF_SWP   = 33792,    // 512 per-block sum(w)
  OFF_SEWP  = 34304,    // 512 per-block sum(w*err)
  OFF_FPART = 34816,    // 3*512 final partials (bce, sum_pi, sum_pi*klog)
  OFF_BBAR  = 36352,    // 8 batches x 512: [0..3]*32 arr | 4*32 root | (8+g)*32 rel
  OFF_TAIL  = 40448,    // last-block-done counter (padded slot)
  OFF_END   = 40480
};

__device__ __forceinline__ float fexp2(float x){ return __builtin_amdgcn_exp2f(x); }
__device__ __forceinline__ float flog2(float x){ return __builtin_amdgcn_logf(x); }
__device__ __forceinline__ v2f vfma(v2f a, v2f b, v2f c){
  return __builtin_elementwise_fma(a,b,c);
}

// L3-coherent access (relaxed agent atomics: cache-bypass, no maintenance)
__device__ __forceinline__ float ld3(const float* p){
  return __hip_atomic_load(p, __ATOMIC_RELAXED, __HIP_MEMORY_SCOPE_AGENT);
}
__device__ __forceinline__ v2f ld3x2(const float* p){   // 8B-aligned pair
  const unsigned long long u =
      __hip_atomic_load(reinterpret_cast<const unsigned long long*>(p),
                        __ATOMIC_RELAXED, __HIP_MEMORY_SCOPE_AGENT);
  return __builtin_bit_cast(v2f, u);
}
__device__ __forceinline__ void st3(float* p, float v){
  __hip_atomic_store(p, v, __ATOMIC_RELAXED, __HIP_MEMORY_SCOPE_AGENT);
}

__device__ __forceinline__ float wave_sum(float v){
  #pragma unroll
  for(int m=32;m;m>>=1) v += __shfl_xor(v,m,64);
  return v;
}
__device__ __forceinline__ float wave_max(float v){
  #pragma unroll
  for(int m=32;m;m>>=1) v = fmaxf(v,__shfl_xor(v,m,64));
  return v;
}

// per-batch fence-free barrier: 64 blocks, 4 groups of 16 -> root ->
// 4 release flags; leaders spin on own group's flag (16 pollers/line).
__device__ __forceinline__ void bbar(unsigned* bbase, int phase, int blk){
  __syncthreads();
  if(threadIdx.x == 0){
    asm volatile("s_waitcnt vmcnt(0)" ::: "memory");   // stores reached L3
    const int g = (blk>>4)&3;
    unsigned* garr = bbase + g*32;
    unsigned* root = bbase + 4*32;
    unsigned* grel = bbase + (8+g)*32;
    const unsigned va = __hip_atomic_fetch_add(garr, 1u, __ATOMIC_RELAXED,
                                               __HIP_MEMORY_SCOPE_AGENT);
    if(va == (unsigned)(16*phase - 1)){
      const unsigned vr = __hip_atomic_fetch_add(root, 1u, __ATOMIC_RELAXED,
                                                 __HIP_MEMORY_SCOPE_AGENT);
      if(vr == (unsigned)(4*phase - 1)){
        #pragma unroll
        for(int g2=0; g2<4; ++g2)
          __hip_atomic_store(bbase + (8+g2)*32, (unsigned)phase,
                             __ATOMIC_RELAXED, __HIP_MEMORY_SCOPE_AGENT);
      }
    }
    while(__hip_atomic_load(grel, __ATOMIC_RELAXED, __HIP_MEMORY_SCOPE_AGENT)
          < (unsigned)phase)
      __builtin_amdgcn_s_sleep(1);
    asm volatile("" ::: "memory");
  }
  __syncthreads();
}

__global__ __launch_bounds__(256) void k_init(float* ws){
  unsigned* bar = reinterpret_cast<unsigned*>(ws);
  for(int i=threadIdx.x; i<OFF_END-OFF_BBAR; i+=256) bar[OFF_BBAR+i] = 0u;
}

// one lse half-iteration, k-pair SoA. Iterated side in LDS scaled
// (xyz = n2sc*xyz pairs, n2 = sc*|.|^2 pairs); swf[p] = n2pair + potential
// (FIRST: wf = SN directly, no copy). Row coefficient pairs hoisted
// (loop-invariant). Per iter: 4 b64 loads + per row {3 pk-fma, 2 exp2,
// 2 add}. Row const sc|row|^2 (pass-correct) in the log2 epilogue.
#define LSE_PASS(ROWV, FIRSTV, PH) {                                          \
    const v2f* SX = ROWV ? sxB : sxA;                                         \
    const v2f* SY = ROWV ? syB : syA;                                         \
    const v2f* SZ = ROWV ? szB : szA;                                         \
    const v2f* SN = ROWV ? n2B : n2A;                                         \
    const float4* AF = ROWV ? AR : AC;                                        \
    float* lo = ws + (ROWV?OFF_LV:OFF_LU) + 2048*b;                           \
    float* op = ws + (ROWV?OFF_LU:OFF_LV);                                    \
    if(!FIRSTV){                                                              \
      for(int s=tid;s<1024;s+=512) swf[s] = SN[s] + ld3x2(lo + 2*s);          \
      __syncthreads();                                                        \
    }                                                                         \
    const v2f* WF = FIRSTV ? SN : swf;                                        \
    const v2f ax0={AF[0].x,AF[0].x}, ay0={AF[0].y,AF[0].y}, az0={AF[0].z,AF[0].z};\
    const v2f ax1={AF[1].x,AF[1].x}, ay1={AF[1].y,AF[1].y}, az1={AF[1].z,AF[1].z};\
    const v2f ax2={AF[2].x,AF[2].x}, ay2={AF[2].y,AF[2].y}, az2={AF[2].z,AF[2].z};\
    const v2f ax3={AF[3].x,AF[3].x}, ay3={AF[3].y,AF[3].y}, az3={AF[3].z,AF[3].z};\
    float sl0=0,sh0=0,sl1=0,sh1=0,sl2=0,sh2=0,sl3=0,sh3=0;                    \
    _Pragma("unroll 2")                                                       \
    for(int p=lane;p<1024;p+=64){                                             \
      const v2f xp=SX[p], yp=SY[p], zp=SZ[p], wp=WF[p];                       \
      v2f c;                                                                  \
      c = vfma(ax0,xp,vfma(ay0,yp,vfma(az0,zp,wp)));                          \
      sl0 += fexp2(c[0]); sh0 += fexp2(c[1]);                                 \
      c = vfma(ax1,xp,vfma(ay1,yp,vfma(az1,zp,wp)));                          \
      sl1 += fexp2(c[0]); sh1 += fexp2(c[1]);                                 \
      c = vfma(ax2,xp,vfma(ay2,yp,vfma(az2,zp,wp)));                          \
      sl2 += fexp2(c[0]); sh2 += fexp2(c[1]);                                 \
      c = vfma(ax3,xp,vfma(ay3,yp,vfma(az3,zp,wp)));                          \
      sl3 += fexp2(c[0]); sh3 += fexp2(c[1]);                                 \
    }                                                                         \
    const float s0=wave_sum(sl0+sh0), s1=wave_sum(sl1+sh1);                   \
    const float s2=wave_sum(sl2+sh2), s3=wave_sum(sl3+sh3);                   \
    if(lane==0){                                                              \
      st3(op+r0g  , TAU*((ROWV?la[0]:lb2) - fmaf(sc,AF[0].w,flog2(s0))));     \
      st3(op+r0g+1, TAU*((ROWV?la[1]:lb2) - fmaf(sc,AF[1].w,flog2(s1))));     \
      st3(op+r0g+2, TAU*((ROWV?la[2]:lb2) - fmaf(sc,AF[2].w,flog2(s2))));     \
      st3(op+r0g+3, TAU*((ROWV?la[3]:lb2) - fmaf(sc,AF[3].w,flog2(s3))));     \
    }                                                                         \
    bbar(bbase, PH, blk);                                                     \
  }

__global__ __launch_bounds__(512,4) void k_fused(const float* __restrict__ x0,
                                                 const float* __restrict__ xgt,
                                                 const float* __restrict__ vp,
                                                 const float* __restrict__ ap,
                                                 const float* __restrict__ mxp,
                                                 float* __restrict__ ws,
                                                 float* __restrict__ out){
  __shared__ v2f sxA[1024], syA[1024], szA[1024], n2A[1024];   // A side SoA
  __shared__ v2f sxB[1024], syB[1024], szB[1024], n2B[1024];   // B side SoA
  __shared__ v2f swf[1024];                                    // folded pot
  __shared__ float sa32[32], sla[32], sal[32];
  __shared__ float sred[24], sfin[40];
  __shared__ int   sLast;
  const int blk = blockIdx.x, tid = threadIdx.x, lane = tid&63, wid = tid>>6;
  const int b = blk>>6, j = blk&63;               // batch, block-in-batch
  const int r0l = j*32 + (wid<<2);                // batch-local row of wave
  const int r0g = b*2048 + r0l;                   // global row
  unsigned* bbase = reinterpret_cast<unsigned*>(ws) + OFF_BBAR + b*512;

  // ---- local prep: load batch points raw (SoA pairs), alpha head ----
  for(int s=tid;s<1024;s+=512){
    const int gi = (b*2048 + 2*s)*3;
    const float xa0=x0[gi],  ya0=x0[gi+1], za0=x0[gi+2];
    const float xa1=x0[gi+3],ya1=x0[gi+4], za1=x0[gi+5];
    sxA[s]=(v2f){xa0,xa1}; syA[s]=(v2f){ya0,ya1}; szA[s]=(v2f){za0,za1};
    n2A[s]=(v2f){xa0*xa0+ya0*ya0+za0*za0, xa1*xa1+ya1*ya1+za1*za1};
    const float xb0=xgt[gi],  yb0=xgt[gi+1], zb0=xgt[gi+2];
    const float xb1=xgt[gi+3],yb1=xgt[gi+4], zb1=xgt[gi+5];
    sxB[s]=(v2f){xb0,xb1}; syB[s]=(v2f){yb0,yb1}; szB[s]=(v2f){zb0,zb1};
    n2B[s]=(v2f){xb0*xb0+yb0*yb0+zb0*zb0, xb1*xb1+yb1*yb1+zb1*zb1};
  }
  if(wid == 0){
    float a_=0.0f, w_=0.0f, se_=0.0f;
    if(lane < 32){
      const int row = b*2048 + j*32 + lane;
      const float al = ap[row];
      const float a = 1.0f/(1.0f + fexp2(-10.0f*tanhf(al*0.1f)*LOG2E));
      sa32[lane] = a;
      sla[lane]  = flog2(fmaxf(a,1e-30f));
      sal[lane]  = al;
      const float w = 1.0f/(1.0f + fexp2(-al*LOG2E));
      const float x = x0[row*3], y = x0[row*3+1], z = x0[row*3+2];
      const float tx = mxp[row*3]-x, ty = mxp[row*3+1]-y, tz = mxp[row*3+2]-z;
      const float dx = vp[row*3]-tx, dy = vp[row*3+1]-ty, dz = vp[row*3+2]-tz;
      a_ = a; w_ = w; se_ = (dx*dx+dy*dy+dz*dz)*w;
    }
    const float sa_s = wave_sum(a_), sw_s = wave_sum(w_), sew_s = wave_sum(se_);
    if(lane == 0){
      st3(ws+OFF_SUMAP+blk, sa_s);
      st3(ws+OFF_SWP  +blk, sw_s);
      st3(ws+OFF_SEWP +blk, sew_s);
    }
  }
  __syncthreads();

  // own-row fragments (RAW, persist across passes) + alpha registers
  const float* fxA = (const float*)sxA; const float* fyA = (const float*)syA;
  const float* fzA = (const float*)szA; const float* fnA = (const float*)n2A;
  const float* fxB = (const float*)sxB; const float* fyB = (const float*)syB;
  const float* fzB = (const float*)szB; const float* fnB = (const float*)n2B;
  float4 AR[4], AC[4]; float la[4], av[4], alv[4];
  #pragma unroll
  for(int r=0;r<4;r++){
    const int q = r0l + r;
    AR[r] = make_float4(fxA[q], fyA[q], fzA[q], fnA[q]);
    AC[r] = make_float4(fxB[q], fyB[q], fzB[q], fnB[q]);
    la[r] = sla[(wid<<2)+r]; av[r] = sa32[(wid<<2)+r]; alv[r] = sal[(wid<<2)+r];
  }

  // ---- phase 1: cmax (raw SoA; hoisted -2*row coeffs; +n2a at end) ----
  {
    const v2f h0x={-2*AR[0].x,-2*AR[0].x}, h0y={-2*AR[0].y,-2*AR[0].y}, h0z={-2*AR[0].z,-2*AR[0].z};
    const v2f h1x={-2*AR[1].x,-2*AR[1].x}, h1y={-2*AR[1].y,-2*AR[1].y}, h1z={-2*AR[1].z,-2*AR[1].z};
    const v2f h2x={-2*AR[2].x,-2*AR[2].x}, h2y={-2*AR[2].y,-2*AR[2].y}, h2z={-2*AR[2].z,-2*AR[2].z};
    const v2f h3x={-2*AR[3].x,-2*AR[3].x}, h3y={-2*AR[3].y,-2*AR[3].y}, h3z={-2*AR[3].z,-2*AR[3].z};
    float m0=-1e30f,m1=-1e30f,m2=-1e30f,m3=-1e30f;  // max of (n2b - 2 a.b)
    #pragma unroll 2
    for(int p=lane;p<1024;p+=64){
      const v2f xp=sxB[p], yp=syB[p], zp=szB[p], np=n2B[p];
      v2f c;
      c = vfma(h0x,xp,vfma(h0y,yp,vfma(h0z,zp,np))); m0=fmaxf(m0,fmaxf(c[0],c[1]));
      c = vfma(h1x,xp,vfma(h1y,yp,vfma(h1z,zp,np))); m1=fmaxf(m1,fmaxf(c[0],c[1]));
      c = vfma(h2x,xp,vfma(h2y,yp,vfma(h2z,zp,np))); m2=fmaxf(m2,fmaxf(c[0],c[1]));
      c = vfma(h3x,xp,vfma(h3y,yp,vfma(h3z,zp,np))); m3=fmaxf(m3,fmaxf(c[0],c[1]));
    }
    // clamp at 0 (cost = max(0, n2a + m)); max commutes with +const
    const float c0 = fmaxf(0.0f, AR[0].w + m0), c1 = fmaxf(0.0f, AR[1].w + m1);
    const float c2 = fmaxf(0.0f, AR[2].w + m2), c3 = fmaxf(0.0f, AR[3].w + m3);
    const float cmv = wave_max(fmaxf(fmaxf(c0,c1),fmaxf(c2,c3)));
    if(lane==0) sred[wid] = cmv;
    __syncthreads();
    if(tid==0){
      float m = sred[0];
      #pragma unroll
      for(int i=1;i<8;i++) m = fmaxf(m, sred[i]);
      st3(ws+OFF_CPART+blk, m);
    }
  }
  bbar(bbase, 1, blk);

  // ---- per-batch constants (lane indexes the batch's 64 block partials) ----
  const float cm = wave_max(ld3(ws+OFF_CPART + b*64 + lane));
  const float sc = NEG20LOG2E/(cm + 1e-8f);
  const float n2sc = -2.0f*sc;
  const float sav = wave_sum(ld3(ws+OFF_SUMAP + b*64 + lane));
  const float lb2 = flog2(fmaxf(sav*(1.0f/2048.0f), 1e-30f));

  // ---- rescale LDS SoA in place (xyz *= n2sc, n2 *= sc) ----
  {
    const v2f vs = {n2sc, n2sc}, vc = {sc, sc};
    for(int s=tid;s<1024;s+=512){
      sxA[s]*=vs; syA[s]*=vs; szA[s]*=vs; n2A[s]*=vc;
      sxB[s]*=vs; syB[s]*=vs; szB[s]*=vs; n2B[s]*=vc;
    }
  }
  __syncthreads();

  // ---- phases 2..11: 5 Sinkhorn iterations (row, col), per-batch sync ----
  LSE_PASS(true,  true,  2)
  LSE_PASS(false, false, 3)
  LSE_PASS(true,  false, 4)
  LSE_PASS(false, false, 5)
  LSE_PASS(true,  false, 6)
  LSE_PASS(false, false, 7)
  LSE_PASS(true,  false, 8)
  LSE_PASS(false, false, 9)
  LSE_PASS(true,  false, 10)
  LSE_PASS(false, false, 11)

  // ---- final pi pass: S, Q=Σp·arg, Pw=Σp·wfold, P2=Σp·(sc·n2) per row ----
  // lv = wfold - sc*n2  =>  Σp·lv = Pw - P2
  {
    float* lv = ws + OFF_LV + 2048*b;
    for(int s=tid;s<1024;s+=512)
      swf[s] = n2B[s] + ld3x2(lv + 2*s);
    __syncthreads();
    const v2f ax0={AR[0].x,AR[0].x}, ay0={AR[0].y,AR[0].y}, az0={AR[0].z,AR[0].z};
    const v2f ax1={AR[1].x,AR[1].x}, ay1={AR[1].y,AR[1].y}, az1={AR[1].z,AR[1].z};
    const v2f ax2={AR[2].x,AR[2].x}, ay2={AR[2].y,AR[2].y}, az2={AR[2].z,AR[2].z};
    const v2f ax3={AR[3].x,AR[3].x}, ay3={AR[3].y,AR[3].y}, az3={AR[3].z,AR[3].z};
    float S[4]={0,0,0,0}, Q[4]={0,0,0,0}, Pw[4]={0,0,0,0}, P2[4]={0,0,0,0};
    #pragma unroll 2
    for(int p=lane;p<1024;p+=64){
      const v2f xp=sxB[p], yp=syB[p], zp=szB[p], wp=swf[p], np=n2B[p];
      v2f c; float e0, e1;
      c = vfma(ax0,xp,vfma(ay0,yp,vfma(az0,zp,wp)));
      e0=fexp2(c[0]); e1=fexp2(c[1]);
      S[0]+=e0+e1; Q[0]=fmaf(e0,c[0],fmaf(e1,c[1],Q[0]));
      Pw[0]=fmaf(e0,wp[0],fmaf(e1,wp[1],Pw[0]));
      P2[0]=fmaf(e0,np[0],fmaf(e1,np[1],P2[0]));
      c = vfma(ax1,xp,vfma(ay1,yp,vfma(az1,zp,wp)));
      e0=fexp2(c[0]); e1=fexp2(c[1]);
      S[1]+=e0+e1; Q[1]=fmaf(e0,c[0],fmaf(e1,c[1],Q[1]));
      Pw[1]=fmaf(e0,wp[0],fmaf(e1,wp[1],Pw[1]));
      P2[1]=fmaf(e0,np[0],fmaf(e1,np[1],P2[1]));
      c = vfma(ax2,xp,vfma(ay2,yp,vfma(az2,zp,wp)));
      e0=fexp2(c[0]); e1=fexp2(c[1]);
      S[2]+=e0+e1; Q[2]=fmaf(e0,c[0],fmaf(e1,c[1],Q[2]));
      Pw[2]=fmaf(e0,wp[0],fmaf(e1,wp[1],Pw[2]));
      P2[2]=fmaf(e0,np[0],fmaf(e1,np[1],P2[2]));
      c = vfma(ax3,xp,vfma(ay3,yp,vfma(az3,zp,wp)));
      e0=fexp2(c[0]); e1=fexp2(c[1]);
      S[3]+=e0+e1; Q[3]=fmaf(e0,c[0],fmaf(e1,c[1],Q[3]));
      Pw[3]=fmaf(e0,wp[0],fmaf(e1,wp[1],Pw[3]));
      P2[3]=fmaf(e0,np[0],fmaf(e1,np[1],P2[3]));
    }
    float spc = 0.0f, bce = 0.0f, spt = 0.0f;
    #pragma unroll
    for(int r=0;r<4;r++){
      const float St = wave_sum(S[r]);
      const float Qt = wave_sum(Q[r]);
      const float Lt = wave_sum(Pw[r]) - wave_sum(P2[r]);   // Σ p·lv
      const float lur = ld3(ws+OFF_LU+r0g+r);
      const float cr = fmaf(sc, AR[r].w, lur);   // hoisted row constant
      const float p2 = fexp2(cr);
      const float sp = p2*St;                    // true row sum of pi
      // sum(pi*arg_true) = p2*(Q + cr*S); klog = arg_true - lu - lv
      spc += p2*fmaf(cr,St,Qt) - p2*Lt - lur*sp;
      float yv = sp / (av[r] + 1e-8f);
      yv = fminf(fmaxf(yv,0.0f),1.0f);
      const float al = alv[r];
      bce += fmaxf(al,0.0f) - al*yv
           + 0.69314718056f*flog2(1.0f + fexp2(-fabsf(al)*LOG2E));
      spt += sp;
    }
    if(lane==0){ sred[wid]=bce; sred[8+wid]=spt; sred[16+wid]=spc; }
    __syncthreads();
    if(tid==0){
      float tb=0, ts=0, tc=0;
      #pragma unroll
      for(int i=0;i<8;i++){ tb+=sred[i]; ts+=sred[8+i]; tc+=sred[16+i]; }
      st3(ws+OFF_FPART +        blk, tb);
      st3(ws+OFF_FPART + 512  + blk, ts);
      st3(ws+OFF_FPART + 1024 + blk, tc);
    }
  }

  // ---- last-block-done combine (tail counter, no global barrier) ----
  __syncthreads();
  if(tid == 0){
    asm volatile("s_waitcnt vmcnt(0)" ::: "memory");  // FPART at L3
    unsigned* tail = reinterpret_cast<unsigned*>(ws) + OFF_TAIL;
    const unsigned v = __hip_atomic_fetch_add(tail, 1u, __ATOMIC_RELAXED,
                                              __HIP_MEMORY_SCOPE_AGENT);
    sLast = (v == 511u) ? 1 : 0;
  }
  __syncthreads();
  if(sLast){
    float pb = ld3(ws+OFF_FPART+tid);
    float ps = ld3(ws+OFF_FPART+512+tid);
    float pc = ld3(ws+OFF_FPART+1024+tid);
    float pw = ld3(ws+OFF_SWP+tid);
    float pe = ld3(ws+OFF_SEWP+tid);
    pb=wave_sum(pb); ps=wave_sum(ps); pc=wave_sum(pc);
    pw=wave_sum(pw); pe=wave_sum(pe);
    if(lane==0){
      sfin[wid*5+0]=pb; sfin[wid*5+1]=ps; sfin[wid*5+2]=pc;
      sfin[wid*5+3]=pw; sfin[wid*5+4]=pe;
    }
    __syncthreads();
    if(tid==0){
      float bce=0, sp=0, spc=0, sw=0, sew=0;
      #pragma unroll
      for(int w=0;w<8;w++){
        bce+=sfin[w*5+0]; sp+=sfin[w*5+1]; spc+=sfin[w*5+2];
        sw +=sfin[w*5+3]; sew+=sfin[w*5+4];
      }
      const float loss_vel  = sew / fmaxf(sw, 1.0f);
      const float loss_surv = bce / 16384.0f;
      // sum(pi*cost_n) = spc * (-ln2/20)  since klog = -20*log2e*cost_n
      const float loss_tr = (spc * (-0.03465735902799726f)) / fmaxf(sp, 1e-8f);
      out[0] = loss_vel + loss_surv + 0.1f*loss_tr;
    }
  }
}

extern "C" void kernel_launch(void* const* d_in, const int* in_sizes, int n_in,
                              void* d_out, int out_size, void* d_ws, size_t ws_size,
                              hipStream_t stream) {
  (void)in_sizes; (void)n_in; (void)out_size; (void)ws_size;
  const float* x0  = (const float*)d_in[0];
  const float* xgt = (const float*)d_in[1];
  const float* vp  = (const float*)d_in[2];
  const float* ap  = (const float*)d_in[3];
  const float* mxp = (const float*)d_in[5];   // t (d_in[4]) unused
  float* ws  = (float*)d_ws;
  float* out = (float*)d_out;

  k_init<<<1, 256, 0, stream>>>(ws);          // zero barrier words + tail ctr

  k_fused<<<512, 512, 0, stream>>>(x0, xgt, vp, ap, mxp, ws, out);
}